// Round 4
// baseline (210.471 us; speedup 1.0000x reference)
//
#include <hip/hip_runtime.h>

typedef short short8 __attribute__((ext_vector_type(8)));
typedef short short4v __attribute__((ext_vector_type(4)));
typedef float floatx4 __attribute__((ext_vector_type(4)));

#define INF 4096

// fp32 -> bf16 round-to-nearest-even
__device__ __forceinline__ ushort f2bf(float f) {
  unsigned u = __builtin_bit_cast(unsigned, f);
  u += 0x7fffu + ((u >> 16) & 1u);
  return (ushort)(u >> 16);
}

// Block-diagonal GEMM, v4: v3 structure + 2 WG/CU co-residency.
// Round-3 post-mortem: traffic was ideal but Occupancy=19.5% (1 WG/CU), and the
// per-tile __syncthreads (vmcnt(0) drain incl. 128 scattered store transactions)
// silenced the whole CU. Fix: grid 512 = 16 k-blocks x 32 m-groups (512 rows),
// 2 WG/CU x 8 waves = 16 waves/CU -- while one WG drains at its barrier, the
// other issues loads/MFMA (m114 wave-level overlap).
// W_k: registers. Wave w owns out-cols [w*32, w*32+32): 16 short8 frags.
// x: LDS-staged 64-row x 256-k bf16 tiles (32 KB x2 buffers), global loads are
//    one full contiguous 1 KB row per wave instruction.
// MFMA: swapped operands mfma(W, x) -> D[n][m], dwordx4 bias+store.
__global__ __launch_bounds__(512, 4) void bd_gemm(
    const float* __restrict__ x, const float* __restrict__ W,
    const float* __restrict__ bias, float* __restrict__ out)
{
  __shared__ ushort xlds[2][64 * 256];  // [buf][row][k] bf16, 16B-chunk XOR swizzle

  const int bid  = blockIdx.x;
  const int kb   = bid & 15;   // low bits: each XCD holds 2 W-blocks in L2
  const int mg   = bid >> 4;   // 0..31, 512 rows each
  const int tid  = threadIdx.x;
  const int lane = tid & 63;
  const int w    = tid >> 6;   // wave 0..7 -> out-col slice
  const int ln   = lane & 15;
  const int lk   = lane >> 4;  // 0..3

  const float* xbase = x   + (size_t)(mg * 512) * INF + kb * 256;
  float*       obase = out + (size_t)(mg * 512) * INF + kb * 256 + w * 32;

  floatx4 g[2][8];  // reg staging: 8 rows/wave/tile, 16B/lane

  // one wave instruction = one contiguous 1KB row read
#define LOADX(set, t)                                                         \
  _Pragma("unroll") for (int i = 0; i < 8; ++i)                               \
    g[set][i] = *(const floatx4*)(xbase + (size_t)((t) * 64 + w * 8 + i) * INF + lane * 4);

  // cvt + swizzled LDS write; one wave instruction = one 512B row
#define WRITEX(set, buf)                                                      \
  _Pragma("unroll") for (int i = 0; i < 8; ++i) {                             \
    const int lr = w * 8 + i;                                                 \
    short4v u;                                                                \
    _Pragma("unroll") for (int j = 0; j < 4; ++j) u[j] = (short)f2bf(g[set][i][j]); \
    *(short4v*)((char*)&xlds[buf][0] +                                        \
        lr * 512 + ((((lane >> 1) ^ (lr & 7)) << 4) | ((lane & 1) << 3))) = u; \
  }

  // compute + store one 64-row tile from LDS buf
#define COMPUTE(buf, t)                                                       \
  {                                                                           \
    floatx4 acc[8];                                                           \
    _Pragma("unroll") for (int a = 0; a < 8; ++a)                             \
      _Pragma("unroll") for (int e = 0; e < 4; ++e) acc[a][e] = 0.0f;         \
    _Pragma("unroll") for (int kc = 0; kc < 8; ++kc) {                        \
      short8 xf[4];                                                           \
      _Pragma("unroll") for (int mi = 0; mi < 4; ++mi) {                      \
        const int lr = mi * 16 + ln;                                          \
        xf[mi] = *(const short8*)((const char*)&xlds[buf][0] +                \
                 lr * 512 + (((kc * 4 + lk) ^ (lr & 7)) << 4));               \
      }                                                                       \
      _Pragma("unroll") for (int mi = 0; mi < 4; ++mi)                        \
        _Pragma("unroll") for (int ni = 0; ni < 2; ++ni)                      \
          acc[mi * 2 + ni] = __builtin_amdgcn_mfma_f32_16x16x32_bf16(         \
              wf[ni][kc], xf[mi], acc[mi * 2 + ni], 0, 0, 0);                 \
    }                                                                         \
    _Pragma("unroll") for (int mi = 0; mi < 4; ++mi)                          \
      _Pragma("unroll") for (int ni = 0; ni < 2; ++ni) {                      \
        floatx4 r = acc[mi * 2 + ni];                                         \
        _Pragma("unroll") for (int j = 0; j < 4; ++j) r[j] += bv[ni][j];      \
        *(floatx4*)(obase + (size_t)((t) * 64 + mi * 16 + ln) * INF +         \
                    ni * 16 + lk * 4) = r;                                    \
      }                                                                       \
  }

  // ---- prologue: x tile-0 loads first (latency hidden by W-frag setup) ----
  LOADX(0, 0)

  // W frags: wave w cols [w*32, w*32+32): A-operand layout A[row=ln][k=lk*8+e]
  short8 wf[2][8];
  {
    const float* wp = W + (size_t)kb * 65536 + (w * 32 + ln) * 256 + lk * 8;
#pragma unroll
    for (int ni = 0; ni < 2; ++ni)
#pragma unroll
      for (int kc = 0; kc < 8; ++kc) {
        const float* s = wp + ni * 16 * 256 + kc * 32;
        floatx4 v0 = *(const floatx4*)s;
        floatx4 v1 = *(const floatx4*)(s + 4);
        short8 u;
#pragma unroll
        for (int j = 0; j < 4; ++j) {
          u[j]     = (short)f2bf(v0[j]);
          u[4 + j] = (short)f2bf(v1[j]);
        }
        wf[ni][kc] = u;
      }
  }
  floatx4 bv[2];
#pragma unroll
  for (int ni = 0; ni < 2; ++ni)
    bv[ni] = *(const floatx4*)(bias + kb * 256 + w * 32 + ni * 16 + lk * 4);

  WRITEX(0, 0)
  __syncthreads();

  // ---- main loop: 8 tiles of 64 rows, reg+LDS double-buffered ----
  for (int tt = 0; tt < 4; ++tt) {
    const int t0 = tt * 2, t1 = tt * 2 + 1;
    LOADX(1, t1)                 // issue next loads before compute: vmcnt wait
    COMPUTE(0, t0)               //   for them never sits behind these stores
    WRITEX(1, 1)
    __syncthreads();
    if (t1 < 7) LOADX(0, t1 + 1)
    COMPUTE(1, t1)
    if (t1 < 7) {
      WRITEX(0, 0)
      __syncthreads();
    }
  }

#undef LOADX
#undef WRITEX
#undef COMPUTE
}

extern "C" void kernel_launch(void* const* d_in, const int* in_sizes, int n_in,
                              void* d_out, int out_size, void* d_ws, size_t ws_size,
                              hipStream_t stream) {
  const float* x = (const float*)d_in[0];
  const float* W = (const float*)d_in[1];
  const float* b = (const float*)d_in[2];
  float* out = (float*)d_out;
  // 16 k-blocks x 32 m-groups = 512 WGs (2/CU), 512 threads (8 waves)
  hipLaunchKernelGGL(bd_gemm, dim3(512), dim3(512), 0, stream, x, W, b, out);
}

// Round 5
// 136.757 us; speedup vs baseline: 1.5390x; 1.5390x over previous
//
#include <hip/hip_runtime.h>

typedef short short8 __attribute__((ext_vector_type(8)));
typedef short short4v __attribute__((ext_vector_type(4)));
typedef float floatx4 __attribute__((ext_vector_type(4)));

#define INF 4096

// fp32 -> bf16 round-to-nearest-even
__device__ __forceinline__ ushort f2bf(float f) {
  unsigned u = __builtin_bit_cast(unsigned, f);
  u += 0x7fffu + ((u >> 16) & 1u);
  return (ushort)(u >> 16);
}

// Block-diagonal GEMM, v5 = v3 registers + v4 grid.
// Round-4 post-mortem: __launch_bounds__(512,4) acted as 4 WGs/CU -> 64-VGPR cap
// -> ~170 live VGPRs spilled to scratch (WRITE_SIZE 262->479 MB). Round-3's real
// limiter was grid=256 (1 WG/CU), not launch_bounds. Fix: grid=512 WGs
// (16 k-blocks x 32 m-groups of 512 rows) with the (512,1) allocation (112 VGPR
// <= 128 -> 4 waves/SIMD; LDS 64 KB x 2 <= 160 KB) so TWO WGs co-reside per CU:
// while one WG drains vmcnt at its barrier, the other issues loads/MFMA.
// W_k: registers. Wave w owns out-cols [w*32, w*32+32): 16 short8 frags.
// x: LDS-staged 64-row x 256-k bf16 tiles (32 KB x2), global loads are one
//    contiguous 1 KB row per wave instruction.
// MFMA: swapped operands mfma(W, x) -> D[n][m], dwordx4 bias+store.
__global__ __launch_bounds__(512, 1) void bd_gemm(
    const float* __restrict__ x, const float* __restrict__ W,
    const float* __restrict__ bias, float* __restrict__ out)
{
  __shared__ ushort xlds[2][64 * 256];  // [buf][row][k] bf16, 16B-chunk XOR swizzle

  const int bid  = blockIdx.x;
  const int kb   = bid & 15;   // xcd = bid%8 = kb%8 -> each XCD holds kb {x, x+8}: W L2-resident
  const int mg   = bid >> 4;   // 0..31, 512 rows each
  const int tid  = threadIdx.x;
  const int lane = tid & 63;
  const int w    = tid >> 6;   // wave 0..7 -> out-col slice
  const int ln   = lane & 15;
  const int lk   = lane >> 4;  // 0..3

  const float* xbase = x   + (size_t)(mg * 512) * INF + kb * 256;
  float*       obase = out + (size_t)(mg * 512) * INF + kb * 256 + w * 32;

  floatx4 g[2][8];  // reg staging: 8 rows/wave/tile, 16B/lane

  // one wave instruction = one contiguous 1KB row read
#define LOADX(set, t)                                                         \
  _Pragma("unroll") for (int i = 0; i < 8; ++i)                               \
    g[set][i] = *(const floatx4*)(xbase + (size_t)((t) * 64 + w * 8 + i) * INF + lane * 4);

  // cvt + swizzled LDS write; one wave instruction = one 512B row
#define WRITEX(set, buf)                                                      \
  _Pragma("unroll") for (int i = 0; i < 8; ++i) {                             \
    const int lr = w * 8 + i;                                                 \
    short4v u;                                                                \
    _Pragma("unroll") for (int j = 0; j < 4; ++j) u[j] = (short)f2bf(g[set][i][j]); \
    *(short4v*)((char*)&xlds[buf][0] +                                        \
        lr * 512 + ((((lane >> 1) ^ (lr & 7)) << 4) | ((lane & 1) << 3))) = u; \
  }

  // compute + store one 64-row tile from LDS buf
#define COMPUTE(buf, t)                                                       \
  {                                                                           \
    floatx4 acc[8];                                                           \
    _Pragma("unroll") for (int a = 0; a < 8; ++a)                             \
      _Pragma("unroll") for (int e = 0; e < 4; ++e) acc[a][e] = 0.0f;         \
    _Pragma("unroll") for (int kc = 0; kc < 8; ++kc) {                        \
      short8 xf[4];                                                           \
      _Pragma("unroll") for (int mi = 0; mi < 4; ++mi) {                      \
        const int lr = mi * 16 + ln;                                          \
        xf[mi] = *(const short8*)((const char*)&xlds[buf][0] +                \
                 lr * 512 + (((kc * 4 + lk) ^ (lr & 7)) << 4));               \
      }                                                                       \
      _Pragma("unroll") for (int mi = 0; mi < 4; ++mi)                        \
        _Pragma("unroll") for (int ni = 0; ni < 2; ++ni)                      \
          acc[mi * 2 + ni] = __builtin_amdgcn_mfma_f32_16x16x32_bf16(         \
              wf[ni][kc], xf[mi], acc[mi * 2 + ni], 0, 0, 0);                 \
    }                                                                         \
    _Pragma("unroll") for (int mi = 0; mi < 4; ++mi)                          \
      _Pragma("unroll") for (int ni = 0; ni < 2; ++ni) {                      \
        floatx4 r = acc[mi * 2 + ni];                                         \
        _Pragma("unroll") for (int j = 0; j < 4; ++j) r[j] += bv[ni][j];      \
        *(floatx4*)(obase + (size_t)((t) * 64 + mi * 16 + ln) * INF +         \
                    ni * 16 + lk * 4) = r;                                    \
      }                                                                       \
  }

  // ---- prologue: x tile-0 loads first (latency hidden by W-frag setup) ----
  LOADX(0, 0)

  // W frags: wave w cols [w*32, w*32+32): A-operand layout A[row=ln][k=lk*8+e]
  short8 wf[2][8];
  {
    const float* wp = W + (size_t)kb * 65536 + (w * 32 + ln) * 256 + lk * 8;
#pragma unroll
    for (int ni = 0; ni < 2; ++ni)
#pragma unroll
      for (int kc = 0; kc < 8; ++kc) {
        const float* s = wp + ni * 16 * 256 + kc * 32;
        floatx4 v0 = *(const floatx4*)s;
        floatx4 v1 = *(const floatx4*)(s + 4);
        short8 u;
#pragma unroll
        for (int j = 0; j < 4; ++j) {
          u[j]     = (short)f2bf(v0[j]);
          u[4 + j] = (short)f2bf(v1[j]);
        }
        wf[ni][kc] = u;
      }
  }
  floatx4 bv[2];
#pragma unroll
  for (int ni = 0; ni < 2; ++ni)
    bv[ni] = *(const floatx4*)(bias + kb * 256 + w * 32 + ni * 16 + lk * 4);

  WRITEX(0, 0)
  __syncthreads();

  // ---- main loop: 8 tiles of 64 rows, reg+LDS double-buffered ----
  for (int tt = 0; tt < 4; ++tt) {
    const int t0 = tt * 2, t1 = tt * 2 + 1;
    LOADX(1, t1)                 // issue next loads before compute: vmcnt wait
    COMPUTE(0, t0)               //   for them never sits behind these stores
    WRITEX(1, 1)
    __syncthreads();
    if (t1 < 7) LOADX(0, t1 + 1)
    COMPUTE(1, t1)
    if (t1 < 7) {
      WRITEX(0, 0)
      __syncthreads();
    }
  }

#undef LOADX
#undef WRITEX
#undef COMPUTE
}

extern "C" void kernel_launch(void* const* d_in, const int* in_sizes, int n_in,
                              void* d_out, int out_size, void* d_ws, size_t ws_size,
                              hipStream_t stream) {
  const float* x = (const float*)d_in[0];
  const float* W = (const float*)d_in[1];
  const float* b = (const float*)d_in[2];
  float* out = (float*)d_out;
  // 16 k-blocks x 32 m-groups = 512 WGs (2 co-resident per CU), 512 threads
  hipLaunchKernelGGL(bd_gemm, dim3(512), dim3(512), 0, stream, x, W, b, out);
}

// Round 6
// 134.118 us; speedup vs baseline: 1.5693x; 1.0197x over previous
//
#include <hip/hip_runtime.h>

typedef short short8 __attribute__((ext_vector_type(8)));
typedef short short4v __attribute__((ext_vector_type(4)));
typedef float floatx4 __attribute__((ext_vector_type(4)));

#define INF 4096

// fp32 -> bf16 round-to-nearest-even
__device__ __forceinline__ ushort f2bf(float f) {
  unsigned u = __builtin_bit_cast(unsigned, f);
  u += 0x7fffu + ((u >> 16) & 1u);
  return (ushort)(u >> 16);
}

// Block-diagonal GEMM, v6 = v5 with SINGLE global-staging register set.
// Round-5 post-mortem: grid 512 changed nothing (occupancy stuck at 21% = 1
// WG/CU).  Reconciliation with round 4 (VGPR=64 -> 40%): rocprof VGPR_Count
// excludes the 32 AGPRs holding acc[8] (gfx950 unified file counts them).
// True per-wave alloc was 112+32=144 -> 3 waves/SIMD -> a 2nd 8-wave WG (needs
// 4/SIMD) can't land.  Fix: drop g[2][8] (64 VGPR) to g[8] (32) -> ~80+32=112
// <= 128 -> 4 waves/SIMD -> 2 WGs/CU co-resident; cross-WG overlap hides each
// WG's barrier vmcnt drain.  Pipeline per tile keeps load-issue -> vmcnt-wait
// distance = one COMPUTE: LOADX(t+1); COMPUTE(t); WRITEX(t+1); barrier.
// W_k: registers. Wave w owns out-cols [w*32, w*32+32): 16 short8 frags.
// x: LDS-staged 64-row x 256-k bf16 tiles (32 KB x2 buffers), global loads are
//    one contiguous 1 KB row per wave instruction.
// MFMA: swapped operands mfma(W, x) -> D[n][m], dwordx4 bias+store.
__global__ __launch_bounds__(512, 1) void bd_gemm(
    const float* __restrict__ x, const float* __restrict__ W,
    const float* __restrict__ bias, float* __restrict__ out)
{
  __shared__ ushort xlds[2][64 * 256];  // [buf][row][k] bf16, 16B-chunk XOR swizzle

  const int bid  = blockIdx.x;
  const int kb   = bid & 15;   // xcd = bid%8 -> each XCD holds 2 W-blocks: L2-resident
  const int mg   = bid >> 4;   // 0..31, 512 rows each
  const int tid  = threadIdx.x;
  const int lane = tid & 63;
  const int w    = tid >> 6;   // wave 0..7 -> out-col slice
  const int ln   = lane & 15;
  const int lk   = lane >> 4;  // 0..3

  const float* xbase = x   + (size_t)(mg * 512) * INF + kb * 256;
  float*       obase = out + (size_t)(mg * 512) * INF + kb * 256 + w * 32;

  floatx4 g[8];  // SINGLE staging set: 8 rows/wave/tile, 16B/lane (32 VGPR)

  // one wave instruction = one contiguous 1KB row read
#define LOADX(t)                                                              \
  _Pragma("unroll") for (int i = 0; i < 8; ++i)                               \
    g[i] = *(const floatx4*)(xbase + (size_t)((t) * 64 + w * 8 + i) * INF + lane * 4);

  // cvt + swizzled LDS write; one wave instruction = one 512B row
#define WRITEX(buf)                                                           \
  _Pragma("unroll") for (int i = 0; i < 8; ++i) {                             \
    const int lr = w * 8 + i;                                                 \
    short4v u;                                                                \
    _Pragma("unroll") for (int j = 0; j < 4; ++j) u[j] = (short)f2bf(g[i][j]); \
    *(short4v*)((char*)&xlds[0][0] + (buf) * 32768 +                          \
        lr * 512 + ((((lane >> 1) ^ (lr & 7)) << 4) | ((lane & 1) << 3))) = u; \
  }

  // compute + store one 64-row tile from LDS buf
#define COMPUTE(buf, t)                                                       \
  {                                                                           \
    floatx4 acc[8];                                                           \
    _Pragma("unroll") for (int a = 0; a < 8; ++a)                             \
      _Pragma("unroll") for (int e = 0; e < 4; ++e) acc[a][e] = 0.0f;         \
    _Pragma("unroll") for (int kc = 0; kc < 8; ++kc) {                        \
      short8 xf[4];                                                           \
      _Pragma("unroll") for (int mi = 0; mi < 4; ++mi) {                      \
        const int lr = mi * 16 + ln;                                          \
        xf[mi] = *(const short8*)((const char*)&xlds[0][0] + (buf) * 32768 +  \
                 lr * 512 + (((kc * 4 + lk) ^ (lr & 7)) << 4));               \
      }                                                                       \
      _Pragma("unroll") for (int mi = 0; mi < 4; ++mi)                        \
        _Pragma("unroll") for (int ni = 0; ni < 2; ++ni)                      \
          acc[mi * 2 + ni] = __builtin_amdgcn_mfma_f32_16x16x32_bf16(         \
              wf[ni][kc], xf[mi], acc[mi * 2 + ni], 0, 0, 0);                 \
    }                                                                         \
    _Pragma("unroll") for (int mi = 0; mi < 4; ++mi)                          \
      _Pragma("unroll") for (int ni = 0; ni < 2; ++ni) {                      \
        floatx4 r = acc[mi * 2 + ni];                                         \
        _Pragma("unroll") for (int j = 0; j < 4; ++j) r[j] += bv[ni][j];      \
        *(floatx4*)(obase + (size_t)((t) * 64 + mi * 16 + ln) * INF +         \
                    ni * 16 + lk * 4) = r;                                    \
      }                                                                       \
  }

  // ---- prologue: x tile-0 loads first (latency hidden by W-frag setup) ----
  LOADX(0)

  // W frags: wave w cols [w*32, w*32+32): A-operand layout A[row=ln][k=lk*8+e]
  short8 wf[2][8];
  {
    const float* wp = W + (size_t)kb * 65536 + (w * 32 + ln) * 256 + lk * 8;
#pragma unroll
    for (int ni = 0; ni < 2; ++ni)
#pragma unroll
      for (int kc = 0; kc < 8; ++kc) {
        const float* s = wp + ni * 16 * 256 + kc * 32;
        floatx4 v0 = *(const floatx4*)s;
        floatx4 v1 = *(const floatx4*)(s + 4);
        short8 u;
#pragma unroll
        for (int j = 0; j < 4; ++j) {
          u[j]     = (short)f2bf(v0[j]);
          u[4 + j] = (short)f2bf(v1[j]);
        }
        wf[ni][kc] = u;
      }
  }
  floatx4 bv[2];
#pragma unroll
  for (int ni = 0; ni < 2; ++ni)
    bv[ni] = *(const floatx4*)(bias + kb * 256 + w * 32 + ni * 16 + lk * 4);

  WRITEX(0)
  __syncthreads();

  // ---- main loop: 8 tiles of 64 rows; LDS double-buffered, g single-set ----
  for (int t = 0; t < 8; ++t) {
    if (t < 7) LOADX(t + 1)      // issue next loads; COMPUTE below hides latency
    COMPUTE(t & 1, t)
    if (t < 7) {
      WRITEX((t + 1) & 1)        // vmcnt-wait for g sits after a full COMPUTE
      __syncthreads();
    }
  }

#undef LOADX
#undef WRITEX
#undef COMPUTE
}

extern "C" void kernel_launch(void* const* d_in, const int* in_sizes, int n_in,
                              void* d_out, int out_size, void* d_ws, size_t ws_size,
                              hipStream_t stream) {
  const float* x = (const float*)d_in[0];
  const float* W = (const float*)d_in[1];
  const float* b = (const float*)d_in[2];
  float* out = (float*)d_out;
  // 16 k-blocks x 32 m-groups = 512 WGs (2 co-resident per CU), 512 threads
  hipLaunchKernelGGL(bd_gemm, dim3(512), dim3(512), 0, stream, x, W, b, out);
}

// Round 8
// 114.053 us; speedup vs baseline: 1.8454x; 1.1759x over previous
//
#include <hip/hip_runtime.h>

typedef short short8 __attribute__((ext_vector_type(8)));
typedef float floatx4 __attribute__((ext_vector_type(4)));
typedef int intx4 __attribute__((ext_vector_type(4)));

#define INF 4096
#define TROWS 32
#define RSTRIDE 1040              // 1024 B row + 16 B pad: bank-quad shift 1/row -> conflict-free frag reads
#define TBYTES (TROWS * RSTRIDE)  // 33280 B per buffer

// fp32 -> bf16 round-to-nearest-even (W prologue only)
__device__ __forceinline__ ushort f2bf(float f) {
  unsigned u = __builtin_bit_cast(unsigned, f);
  u += 0x7fffu + ((u >> 16) & 1u);
  return (ushort)(u >> 16);
}

// Block-diagonal GEMM v7: deep-prefetch pipeline, no vmcnt(0) in the main loop.
// Rounds 3/5/6 all sat at ~134us regardless of occupancy: __syncthreads drains
// vmcnt to 0 every tile -> bursty load stream -> ~3 TB/s. v7 removes the drain:
//  - x staged fp32 via global_load_lds (1 KB row / instruction, no reg staging)
//  - 4 LDS buffers (133 KB), prefetch depth 3 (~12 KB in flight per wave always)
//  - asm s_waitcnt vmcnt(8) + raw s_barrier (+compiler fences): counted wait;
//    loads complete in order, so <=8 outstanding with 8 newer loads in flight
//    certifies tile-t resident; stores in the counter only strengthen the wait.
//  - store of tile t-1 deferred past iteration t's barrier (double accumulator)
//    so stores are ~1 full compute old at every wait point.
//  - fp32->bf16 on read via v_cvt_pk_bf16_f32 (4 VALU per frag).
// W_k in registers (wave w owns cols [w*32,w*32+32), 16 short8), swapped-operand
// MFMA mfma(W, x) -> D[n][m], dwordx4 bias+store. Grid 256 = 16 kb x 16 mg; 1
// WG/CU by design (depth replaces occupancy).
// (Round 7 was an infra failure -- UnresponsiveContainer before any run; this
// is the same kernel resubmitted after a correctness/hang re-audit.)
__global__ __launch_bounds__(512, 1) void bd_gemm(
    const float* __restrict__ x, const float* __restrict__ W,
    const float* __restrict__ bias, float* __restrict__ out)
{
  __shared__ __align__(16) char xlds[4 * TBYTES];  // 133,120 B

  const int bid  = blockIdx.x;
  const int kb   = bid & 15;   // xcd = bid%8 -> each XCD serves kb {x, x+8}: W stays L2-resident
  const int mg   = bid >> 4;   // 0..15, 1024 rows each
  const int tid  = threadIdx.x;
  const int lane = tid & 63;
  const int w    = tid >> 6;   // wave 0..7 -> out-col slice
  const int ln   = lane & 15;
  const int lk   = lane >> 4;  // 0..3

  const float* xbase = x   + (size_t)(mg * 1024) * INF + kb * 256;
  float*       obase = out + (size_t)(mg * 1024) * INF + kb * 256 + w * 32;

#define WAITVM(N) asm volatile("s_waitcnt vmcnt(" #N ")" ::: "memory")
#define BAR()                                                                 \
  do {                                                                        \
    asm volatile("" ::: "memory");                                            \
    __builtin_amdgcn_s_barrier();                                             \
    asm volatile("" ::: "memory");                                            \
  } while (0)

  // one instruction = one contiguous 1 KB fp32 row -> LDS (lane*16 implicit dest)
#define PREFETCH(t)                                                           \
  _Pragma("unroll") for (int i_ = 0; i_ < 4; ++i_) {                          \
    const int r_ = w * 4 + i_;                                                \
    const float* gp_ = xbase + (size_t)((t) * TROWS + r_) * INF + lane * 4;   \
    __builtin_amdgcn_global_load_lds(                                         \
        (const __attribute__((address_space(1))) float*)gp_,                  \
        (__attribute__((address_space(3))) float*)(                           \
            xlds + ((t) & 3) * TBYTES + r_ * RSTRIDE),                        \
        16, 0, 0);                                                            \
  }

  // read fp32 frags from LDS, cvt_pk -> bf16, 32 MFMA per tile per wave
#define COMPUTE(t, accv)                                                      \
  {                                                                           \
    const char* bb_ = xlds + ((t) & 3) * TBYTES;                              \
    _Pragma("unroll") for (int a_ = 0; a_ < 4; ++a_)                          \
      _Pragma("unroll") for (int e_ = 0; e_ < 4; ++e_) accv[a_][e_] = 0.0f;   \
    _Pragma("unroll") for (int kc_ = 0; kc_ < 8; ++kc_) {                     \
      short8 xf_[2];                                                          \
      _Pragma("unroll") for (int mi_ = 0; mi_ < 2; ++mi_) {                   \
        const char* fp_ = bb_ + (mi_ * 16 + ln) * RSTRIDE + kc_ * 128 + lk * 32; \
        floatx4 v0_ = *(const floatx4*)fp_;                                   \
        floatx4 v1_ = *(const floatx4*)(fp_ + 16);                            \
        unsigned p0_, p1_, p2_, p3_;                                          \
        asm("v_cvt_pk_bf16_f32 %0, %1, %2" : "=v"(p0_) : "v"(v0_[0]), "v"(v0_[1])); \
        asm("v_cvt_pk_bf16_f32 %0, %1, %2" : "=v"(p1_) : "v"(v0_[2]), "v"(v0_[3])); \
        asm("v_cvt_pk_bf16_f32 %0, %1, %2" : "=v"(p2_) : "v"(v1_[0]), "v"(v1_[1])); \
        asm("v_cvt_pk_bf16_f32 %0, %1, %2" : "=v"(p3_) : "v"(v1_[2]), "v"(v1_[3])); \
        intx4 d_;                                                             \
        d_[0] = (int)p0_; d_[1] = (int)p1_; d_[2] = (int)p2_; d_[3] = (int)p3_; \
        xf_[mi_] = __builtin_bit_cast(short8, d_);                            \
      }                                                                       \
      _Pragma("unroll") for (int mi_ = 0; mi_ < 2; ++mi_)                     \
        _Pragma("unroll") for (int ni_ = 0; ni_ < 2; ++ni_)                   \
          accv[mi_ * 2 + ni_] = __builtin_amdgcn_mfma_f32_16x16x32_bf16(      \
              wf[ni_][kc_], xf_[mi_], accv[mi_ * 2 + ni_], 0, 0, 0);          \
    }                                                                         \
  }

  // bias + store one tile (frag: m-col = ln, n-row = lk*4 + j -> dwordx4 over n)
#define STOREACC(t, accv)                                                     \
  _Pragma("unroll") for (int mi_ = 0; mi_ < 2; ++mi_)                         \
    _Pragma("unroll") for (int ni_ = 0; ni_ < 2; ++ni_) {                     \
      floatx4 r_ = accv[mi_ * 2 + ni_];                                       \
      _Pragma("unroll") for (int j_ = 0; j_ < 4; ++j_) r_[j_] += bv[ni_][j_]; \
      *(floatx4*)(obase + (size_t)((t) * TROWS + mi_ * 16 + ln) * INF +       \
                  ni_ * 16 + lk * 4) = r_;                                    \
    }

  // ---- prologue: prefetch tiles 0..2, then W frags + bias (compiler loads
  // drain inside the prologue at the cvt; only builtin loads remain in loop) ----
  PREFETCH(0)
  PREFETCH(1)
  PREFETCH(2)

  short8 wf[2][8];  // wave w cols [w*32, w*32+32): A-layout [row=n (ln)][k=lk*8+e]
  {
    const float* wp = W + (size_t)kb * 65536 + (w * 32 + ln) * 256 + lk * 8;
#pragma unroll
    for (int ni = 0; ni < 2; ++ni)
#pragma unroll
      for (int kc = 0; kc < 8; ++kc) {
        const float* s = wp + ni * 16 * 256 + kc * 32;
        floatx4 v0 = *(const floatx4*)s;
        floatx4 v1 = *(const floatx4*)(s + 4);
        short8 u;
#pragma unroll
        for (int j = 0; j < 4; ++j) {
          u[j]     = (short)f2bf(v0[j]);
          u[4 + j] = (short)f2bf(v1[j]);
        }
        wf[ni][kc] = u;
      }
  }
  floatx4 bv[2];
#pragma unroll
  for (int ni = 0; ni < 2; ++ni)
    bv[ni] = *(const floatx4*)(bias + kb * 256 + w * 32 + ni * 16 + lk * 4);

  floatx4 acc0[4], acc1[4];

  // ---- main loop: 32 tiles, depth-3 prefetch, counted vmcnt, no drains ----
  // wait vmcnt(8): newer loads = tiles t+1,t+2 (8); in-order load completion
  // certifies tile t. barrier certifies all waves' rows + frees buf (t-1)&3.
  WAITVM(8); BAR(); PREFETCH(3); COMPUTE(0, acc0);

#pragma unroll 1
  for (int tt = 0; tt < 14; ++tt) {
    const int t_ = 1 + tt * 2;  // 1,3,...,27
    WAITVM(8); BAR(); PREFETCH(t_ + 3); STOREACC(t_ - 1, acc0); COMPUTE(t_, acc1);
    WAITVM(8); BAR(); PREFETCH(t_ + 4); STOREACC(t_,     acc1); COMPUTE(t_ + 1, acc0);
  }
  // t=29..31: no prefetch left; wait = 4*(31-t) newer loads
  WAITVM(8); BAR(); STOREACC(28, acc0); COMPUTE(29, acc1);
  WAITVM(4); BAR(); STOREACC(29, acc1); COMPUTE(30, acc0);
  WAITVM(0); BAR(); STOREACC(30, acc0); COMPUTE(31, acc1);
  STOREACC(31, acc1);

#undef WAITVM
#undef BAR
#undef PREFETCH
#undef COMPUTE
#undef STOREACC
}

extern "C" void kernel_launch(void* const* d_in, const int* in_sizes, int n_in,
                              void* d_out, int out_size, void* d_ws, size_t ws_size,
                              hipStream_t stream) {
  const float* x = (const float*)d_in[0];
  const float* W = (const float*)d_in[1];
  const float* b = (const float*)d_in[2];
  float* out = (float*)d_out;
  // 16 k-blocks x 16 m-groups = 256 WGs (1/CU by design), 512 threads (8 waves)
  hipLaunchKernelGGL(bd_gemm, dim3(256), dim3(512), 0, stream, x, W, b, out);
}

// Round 11
// 108.532 us; speedup vs baseline: 1.9393x; 1.0509x over previous
//
#include <hip/hip_runtime.h>

typedef short short8 __attribute__((ext_vector_type(8)));
typedef float floatx4 __attribute__((ext_vector_type(4)));
typedef unsigned uint2v __attribute__((ext_vector_type(2)));

#define INF 4096
#define TROWS 32
#define RS 528              // bf16 row stride: 512 B data + 16 B pad -> frag reads 2-way max (free)
#define TB (TROWS * RS)     // 16,896 B per buffer

// fp32 -> bf16 round-to-nearest-even (W prologue only)
__device__ __forceinline__ ushort f2bf(float f) {
  unsigned u = __builtin_bit_cast(unsigned, f);
  u += 0x7fffu + ((u >> 16) & 1u);
  return (ushort)(u >> 16);
}

// Block-diagonal GEMM v10: bf16-in-LDS, compiler-managed vmcnt, raw barrier.
// v9's NaN: hand-counted vmcnt is unsound if the allocator spills (scratch
// VMEM ops pollute the count) -> abandoned hand vmcnt. v7's 114us limiter
// (cycle model): every wave read the full fp32 tile from LDS (256 KB/tile/CU)
// and re-converted every element (512 cvt-instr/tile) -> serial chain ~8550
// cyc/tile vs 6240 HBM service -> HBM 73% duty. v10: reg-stage x, convert
// ONCE, store bf16 to LDS: LDS reads halve, cvt drops 8x. Staging loads stay
// in flight across barriers (raw s_barrier + lgkmcnt(0) only -- no vmcnt(0)
// drain); the compiler's own vmcnt wait for g lands after a full COMPUTE.
// Race audit (2 bufs, 1 barrier/tile): WRITEX(t+1)->buf (t+1)&1, readers
// COMPUTE(t-1) all passed the previous barrier; COMPUTE(t) reads writes
// flushed by lgkmcnt(0)+barrier. No hand vmcnt -> spill-robust.
// W_k in registers (wave w owns out-cols [w*32,w*32+32): wf[2][8] = 64 VGPR).
// Swapped mfma(W, x) -> D[n][m]: lane = 4 consecutive out-cols -> dwordx4.
// Grid 256 = 16 kb x 16 mg (1024 rows = 32 tiles of 32); 512 thr, 1 WG/CU.
__global__ __launch_bounds__(512, 1) void bd_gemm(
    const float* __restrict__ x, const float* __restrict__ W,
    const float* __restrict__ bias, float* __restrict__ out)
{
  __shared__ __align__(16) char xlds[2 * TB];  // 33,792 B

  const int bid  = blockIdx.x;
  const int kb   = bid & 15;   // xcd = bid%8 -> 2 k-blocks per XCD: W L2-resident
  const int mg   = bid >> 4;   // 0..15, 1024 rows each
  const int tid  = threadIdx.x;
  const int lane = tid & 63;
  const int w    = tid >> 6;   // wave 0..7 -> out-col slice of 32
  const int ln   = lane & 15;
  const int lk   = lane >> 4;  // 0..3

  const float* xbase = x   + (size_t)(mg * 1024) * INF + kb * 256;
  float*       obase = out + (size_t)(mg * 1024) * INF + kb * 256 + w * 32;

#define LGKM0_BAR()                                                           \
  do {                                                                        \
    asm volatile("s_waitcnt lgkmcnt(0)" ::: "memory");                        \
    __builtin_amdgcn_s_barrier();                                             \
    asm volatile("" ::: "memory");                                            \
  } while (0)

  floatx4 g[4];  // staging: 4 rows/wave/tile, 16 B/lane (16 VGPR)

  // one instruction = one contiguous 1 KB fp32 row -> regs
#define LOADX(t)                                                              \
  _Pragma("unroll") for (int i_ = 0; i_ < 4; ++i_)                            \
    g[i_] = *(const floatx4*)(xbase + (size_t)((t) * TROWS + w * 4 + i_) * INF + lane * 4);

  // cvt ONCE to bf16, ds_write_b64: row r gets bytes [lane*8, lane*8+8)
#define WRITEX(t)                                                             \
  _Pragma("unroll") for (int i_ = 0; i_ < 4; ++i_) {                          \
    const int r_ = w * 4 + i_;                                                \
    unsigned p0_, p1_;                                                        \
    asm("v_cvt_pk_bf16_f32 %0, %1, %2" : "=v"(p0_) : "v"(g[i_][0]), "v"(g[i_][1])); \
    asm("v_cvt_pk_bf16_f32 %0, %1, %2" : "=v"(p1_) : "v"(g[i_][2]), "v"(g[i_][3])); \
    uint2v u_; u_[0] = p0_; u_[1] = p1_;                                      \
    *(uint2v*)(xlds + ((t) & 1) * TB + r_ * RS + lane * 8) = u_;              \
  }

  // 16 ds_read_b128 + 32 MFMA per tile per wave (frag: x[mi*16+ln][kc*32+lk*8+e])
#define COMPUTE(t)                                                            \
  {                                                                           \
    const char* bb_ = xlds + ((t) & 1) * TB;                                  \
    _Pragma("unroll") for (int a_ = 0; a_ < 4; ++a_)                          \
      _Pragma("unroll") for (int e_ = 0; e_ < 4; ++e_) acc[a_][e_] = 0.0f;    \
    _Pragma("unroll") for (int kc_ = 0; kc_ < 8; ++kc_) {                     \
      short8 xf_[2];                                                          \
      _Pragma("unroll") for (int mi_ = 0; mi_ < 2; ++mi_)                     \
        xf_[mi_] = *(const short8*)(bb_ + (mi_ * 16 + ln) * RS + kc_ * 64 + lk * 16); \
      _Pragma("unroll") for (int mi_ = 0; mi_ < 2; ++mi_)                     \
        _Pragma("unroll") for (int ni_ = 0; ni_ < 2; ++ni_)                   \
          acc[mi_ * 2 + ni_] = __builtin_amdgcn_mfma_f32_16x16x32_bf16(       \
              wf[ni_][kc_], xf_[mi_], acc[mi_ * 2 + ni_], 0, 0, 0);           \
    }                                                                         \
  }

  // frag D[n][m]: m(row) = mi*16 + ln, n(col) = ni*16 + lk*4 + j -> dwordx4
#define STOREACC(t)                                                           \
  _Pragma("unroll") for (int mi_ = 0; mi_ < 2; ++mi_)                         \
    _Pragma("unroll") for (int ni_ = 0; ni_ < 2; ++ni_) {                     \
      floatx4 r_ = acc[mi_ * 2 + ni_];                                        \
      _Pragma("unroll") for (int j_ = 0; j_ < 4; ++j_) r_[j_] += bv[ni_][j_]; \
      *(floatx4*)(obase + (size_t)((t) * TROWS + mi_ * 16 + ln) * INF +       \
                  ni_ * 16 + lk * 4) = r_;                                    \
    }

  // ---- prologue: tile-0 loads first, W frags under their latency ----
  LOADX(0)

  short8 wf[2][8];  // wave w cols [w*32, w*32+32): A-layout [row=n (ln)][k=lk*8+e]
  {
    const float* wp = W + (size_t)kb * 65536 + (w * 32 + ln) * 256 + lk * 8;
#pragma unroll
    for (int ni = 0; ni < 2; ++ni)
#pragma unroll
      for (int kc = 0; kc < 8; ++kc) {
        const float* s = wp + ni * 16 * 256 + kc * 32;
        floatx4 v0 = *(const floatx4*)s;
        floatx4 v1 = *(const floatx4*)(s + 4);
        short8 u;
#pragma unroll
        for (int j = 0; j < 4; ++j) {
          u[j]     = (short)f2bf(v0[j]);
          u[4 + j] = (short)f2bf(v1[j]);
        }
        wf[ni][kc] = u;
      }
  }
  floatx4 bv[2];
#pragma unroll
  for (int ni = 0; ni < 2; ++ni)
    bv[ni] = *(const floatx4*)(bias + kb * 256 + w * 32 + ni * 16 + lk * 4);

  floatx4 acc[4];

  WRITEX(0)        // compiler's vmcnt wait for g sits here (after W prologue)
  LGKM0_BAR();

  // ---- main loop: 32 tiles, 1 barrier/tile, staging loads cross barriers ----
#pragma unroll 1
  for (int t = 0; t < 32; ++t) {
    if (t < 31) LOADX(t + 1)   // issue next rows; vmcnt wait lands in WRITEX below
    COMPUTE(t)
    STOREACC(t)
    if (t < 31) {
      WRITEX(t + 1)            // cvt once; ds_write bf16 into buf (t+1)&1
      LGKM0_BAR();             // ds_writes visible; NO vmcnt drain
    }
  }

#undef LGKM0_BAR
#undef LOADX
#undef WRITEX
#undef COMPUTE
#undef STOREACC
}

extern "C" void kernel_launch(void* const* d_in, const int* in_sizes, int n_in,
                              void* d_out, int out_size, void* d_ws, size_t ws_size,
                              hipStream_t stream) {
  const float* x = (const float*)d_in[0];
  const float* W = (const float*)d_in[1];
  const float* b = (const float*)d_in[2];
  float* out = (float*)d_out;
  // 16 k-blocks x 16 m-groups = 256 WGs (1/CU), 512 threads (8 waves)
  hipLaunchKernelGGL(bd_gemm, dim3(256), dim3(512), 0, stream, x, W, b, out);
}